// Round 2
// baseline (1488.513 us; speedup 1.0000x reference)
//
#include <hip/hip_runtime.h>
#include <hip/hip_bf16.h>
#include <math.h>

#define DFEAT 128
#define QKD 32
#define CHUNK 2048

static inline size_t align256(size_t x) { return (x + 255) & ~size_t(255); }

// ---- degree / CSC build ------------------------------------------------

__global__ void count_kernel(const int* __restrict__ eidx, unsigned* __restrict__ cnt_row,
                             unsigned* __restrict__ cnt_col, int E) {
    int e = blockIdx.x * blockDim.x + threadIdx.x;
    if (e < E) {
        atomicAdd(&cnt_row[eidx[e]], 1u);       // deg over row (source)
        atomicAdd(&cnt_col[eidx[E + e]], 1u);   // CSC histogram over col (dest)
    }
}

__global__ void dinv_kernel(const unsigned* __restrict__ cnt_row, float* __restrict__ dinv, int n) {
    int i = blockIdx.x * blockDim.x + threadIdx.x;
    if (i < n) {
        unsigned c = cnt_row[i];
        if (c < 1u) c = 1u;                      // clip(deg, 1)
        dinv[i] = 1.0f / sqrtf((float)c);
    }
}

__global__ void chunk_reduce_kernel(const unsigned* __restrict__ cnt, unsigned* __restrict__ chunksum, int n) {
    __shared__ unsigned s[256];
    int base = blockIdx.x * CHUNK;
    unsigned acc = 0;
    for (int i = threadIdx.x; i < CHUNK; i += 256) {
        int g = base + i;
        if (g < n) acc += cnt[g];
    }
    s[threadIdx.x] = acc; __syncthreads();
    for (int off = 128; off > 0; off >>= 1) {
        if (threadIdx.x < off) s[threadIdx.x] += s[threadIdx.x + off];
        __syncthreads();
    }
    if (threadIdx.x == 0) chunksum[blockIdx.x] = s[0];
}

__global__ void scan_chunks_kernel(const unsigned* __restrict__ chunksum, unsigned* __restrict__ chunkoff,
                                   unsigned* __restrict__ colptr, int nchunks, int n, int E) {
    if (threadIdx.x == 0 && blockIdx.x == 0) {
        unsigned acc = 0;
        for (int i = 0; i < nchunks; ++i) { chunkoff[i] = acc; acc += chunksum[i]; }
        colptr[n] = (unsigned)E;
    }
}

__global__ void chunk_scan_kernel(const unsigned* __restrict__ cnt, const unsigned* __restrict__ chunkoff,
                                  unsigned* __restrict__ colptr, int n) {
    __shared__ unsigned s[256];
    int base = blockIdx.x * CHUNK + threadIdx.x * 8;
    unsigned v[8]; unsigned acc = 0;
#pragma unroll
    for (int j = 0; j < 8; ++j) { int g = base + j; v[j] = (g < n) ? cnt[g] : 0u; acc += v[j]; }
    s[threadIdx.x] = acc; __syncthreads();
    for (int off = 1; off < 256; off <<= 1) {
        unsigned t = (threadIdx.x >= (unsigned)off) ? s[threadIdx.x - off] : 0u;
        __syncthreads();
        s[threadIdx.x] += t;
        __syncthreads();
    }
    unsigned prefix = chunkoff[blockIdx.x] + s[threadIdx.x] - acc;  // exclusive
#pragma unroll
    for (int j = 0; j < 8; ++j) { int g = base + j; if (g < n) colptr[g] = prefix; prefix += v[j]; }
}

__global__ void copy_u32_kernel(const unsigned* __restrict__ a, unsigned* __restrict__ b, int n) {
    int i = blockIdx.x * blockDim.x + threadIdx.x;
    if (i < n) b[i] = a[i];
}

__global__ void fill_csc_kernel(const int* __restrict__ eidx, unsigned* __restrict__ cursor,
                                int* __restrict__ rowlist, int E) {
    int e = blockIdx.x * blockDim.x + threadIdx.x;
    if (e < E) {
        int c = eidx[E + e];
        unsigned p = atomicAdd(&cursor[c], 1u);
        rowlist[p] = eidx[e];
    }
}

// ---- query path (atomic-free, two stage) -------------------------------

__global__ void colmean_partial_kernel(const float* __restrict__ h, float* __restrict__ partial, int n) {
    __shared__ float s[256];
    int t = threadIdx.x;
    int col = t & 127;
    int half = t >> 7;
    float acc = 0.f;
    for (int r = blockIdx.x * 2 + half; r < n; r += gridDim.x * 2)
        acc += h[(size_t)r * DFEAT + col];
    s[t] = acc; __syncthreads();
    if (t < 128) partial[(size_t)blockIdx.x * DFEAT + t] = s[t] + s[t + 128];
}

__global__ void wkq_kernel(const float* __restrict__ partial, int nparts,
                           const float* __restrict__ Wq, const float* __restrict__ bq,
                           const float* __restrict__ Wk, const float* __restrict__ bk,
                           float* __restrict__ wkq_ck, float inv_n) {
    __shared__ float hb[DFEAT];
    __shared__ float qg[QKD];
    int t = threadIdx.x;  // 128 threads
    float acc = 0.f;
    for (int b = 0; b < nparts; ++b) acc += partial[(size_t)b * DFEAT + t];
    hb[t] = acc * inv_n;
    __syncthreads();
    if (t < QKD) {
        float a = bq[t];
        for (int d = 0; d < DFEAT; ++d) a += hb[d] * Wq[d * QKD + t];
        qg[t] = a;
    }
    __syncthreads();
    float w = 0.f;
    for (int q = 0; q < QKD; ++q) w += Wk[t * QKD + q] * qg[q];
    wkq_ck[t] = w;
    if (t == 0) {
        float c = 0.f;
        for (int q = 0; q < QKD; ++q) c += bk[q] * qg[q];
        wkq_ck[DFEAT] = c;
    }
}

// ---- propagate + online softmax accumulation ---------------------------
// wave (64 lanes) per dest node; float2/lane = 512B coalesced row reads.
// P(x)[c] = dinv[c] * sum_{in-edges} dinv[r]*x[r]
// hop0: a_feat = x + P(x) (k=0), x1 = x - P(x) (k=1); init {m,den,U}.
// hops 2..7: x_t = x - P(x); update {m,den,U} flash-style.
// U accumulates sum_k exp(s_k - m) * row_k ; lives in d_out.

__device__ __forceinline__ float wave_score2(float px, float py, float wx, float wy,
                                             float ck, float scale) {
    float s = px * wx + py * wy;
#pragma unroll
    for (int off = 32; off > 0; off >>= 1) s += __shfl_xor(s, off, 64);
    return (s + ck) * scale;
}

__global__ void prop0_kernel(const float* __restrict__ x, const int* __restrict__ rowlist,
                             const unsigned* __restrict__ colptr, const float* __restrict__ dinv,
                             const float* __restrict__ wkq_ck,
                             float* __restrict__ xout, float* __restrict__ U,
                             float* __restrict__ m_run, float* __restrict__ den_run, int n) {
    int wid = threadIdx.x >> 6;
    int lane = threadIdx.x & 63;
    int c = blockIdx.x * 4 + wid;
    if (c >= n) return;
    unsigned beg = colptr[c], end = colptr[c + 1];
    float ax = 0.f, ay = 0.f;
    unsigned e = beg;
    for (; e + 4 <= end; e += 4) {
        int r0 = rowlist[e], r1 = rowlist[e + 1], r2 = rowlist[e + 2], r3 = rowlist[e + 3];
        float d0 = dinv[r0], d1 = dinv[r1], d2 = dinv[r2], d3 = dinv[r3];
        float2 v0 = *reinterpret_cast<const float2*>(&x[(size_t)r0 * DFEAT + lane * 2]);
        float2 v1 = *reinterpret_cast<const float2*>(&x[(size_t)r1 * DFEAT + lane * 2]);
        float2 v2 = *reinterpret_cast<const float2*>(&x[(size_t)r2 * DFEAT + lane * 2]);
        float2 v3 = *reinterpret_cast<const float2*>(&x[(size_t)r3 * DFEAT + lane * 2]);
        ax += d0 * v0.x + d1 * v1.x + d2 * v2.x + d3 * v3.x;
        ay += d0 * v0.y + d1 * v1.y + d2 * v2.y + d3 * v3.y;
    }
    for (; e < end; ++e) {
        int r = rowlist[e];
        float di = dinv[r];
        float2 v = *reinterpret_cast<const float2*>(&x[(size_t)r * DFEAT + lane * 2]);
        ax += di * v.x; ay += di * v.y;
    }
    float dc = dinv[c];
    float2 b = *reinterpret_cast<const float2*>(&x[(size_t)c * DFEAT + lane * 2]);
    float addx = b.x + dc * ax, addy = b.y + dc * ay;   // a_feat row (k=0)
    float subx = b.x - dc * ax, suby = b.y - dc * ay;   // x1 row (k=1)

    *reinterpret_cast<float2*>(&xout[(size_t)c * DFEAT + lane * 2]) = make_float2(subx, suby);

    const float scale = 0.08838834764831845f;  // 1/sqrt(128)
    float ck = wkq_ck[DFEAT];
    float2 wk2 = *reinterpret_cast<const float2*>(&wkq_ck[lane * 2]);
    float s0 = wave_score2(addx, addy, wk2.x, wk2.y, ck, scale);
    float s1 = wave_score2(subx, suby, wk2.x, wk2.y, ck, scale);
    float m = fmaxf(s0, s1);
    float e0 = expf(s0 - m), e1 = expf(s1 - m);
    // init U (no read: d_out is poisoned before timing)
    float ux = e0 * addx + e1 * subx;
    float uy = e0 * addy + e1 * suby;
    *reinterpret_cast<float2*>(&U[(size_t)c * DFEAT + lane * 2]) = make_float2(ux, uy);
    if (lane == 0) { m_run[c] = m; den_run[c] = e0 + e1; }
}

__global__ void prop_fused_kernel(const float* __restrict__ x, const int* __restrict__ rowlist,
                                  const unsigned* __restrict__ colptr, const float* __restrict__ dinv,
                                  const float* __restrict__ wkq_ck,
                                  float* __restrict__ xout, float* __restrict__ U,
                                  float* __restrict__ m_run, float* __restrict__ den_run, int n) {
    int wid = threadIdx.x >> 6;
    int lane = threadIdx.x & 63;
    int c = blockIdx.x * 4 + wid;
    if (c >= n) return;
    unsigned beg = colptr[c], end = colptr[c + 1];
    float ax = 0.f, ay = 0.f;
    unsigned e = beg;
    for (; e + 4 <= end; e += 4) {
        int r0 = rowlist[e], r1 = rowlist[e + 1], r2 = rowlist[e + 2], r3 = rowlist[e + 3];
        float d0 = dinv[r0], d1 = dinv[r1], d2 = dinv[r2], d3 = dinv[r3];
        float2 v0 = *reinterpret_cast<const float2*>(&x[(size_t)r0 * DFEAT + lane * 2]);
        float2 v1 = *reinterpret_cast<const float2*>(&x[(size_t)r1 * DFEAT + lane * 2]);
        float2 v2 = *reinterpret_cast<const float2*>(&x[(size_t)r2 * DFEAT + lane * 2]);
        float2 v3 = *reinterpret_cast<const float2*>(&x[(size_t)r3 * DFEAT + lane * 2]);
        ax += d0 * v0.x + d1 * v1.x + d2 * v2.x + d3 * v3.x;
        ay += d0 * v0.y + d1 * v1.y + d2 * v2.y + d3 * v3.y;
    }
    for (; e < end; ++e) {
        int r = rowlist[e];
        float di = dinv[r];
        float2 v = *reinterpret_cast<const float2*>(&x[(size_t)r * DFEAT + lane * 2]);
        ax += di * v.x; ay += di * v.y;
    }
    float dc = dinv[c];
    float2 b = *reinterpret_cast<const float2*>(&x[(size_t)c * DFEAT + lane * 2]);
    float subx = b.x - dc * ax, suby = b.y - dc * ay;
    *reinterpret_cast<float2*>(&xout[(size_t)c * DFEAT + lane * 2]) = make_float2(subx, suby);

    const float scale = 0.08838834764831845f;
    float ck = wkq_ck[DFEAT];
    float2 wk2 = *reinterpret_cast<const float2*>(&wkq_ck[lane * 2]);
    float s = wave_score2(subx, suby, wk2.x, wk2.y, ck, scale);
    float m = m_run[c], den = den_run[c];
    float m2 = fmaxf(m, s);
    float alpha = expf(m - m2), beta = expf(s - m2);
    size_t uoff = (size_t)c * DFEAT + lane * 2;
    float2 u = *reinterpret_cast<const float2*>(&U[uoff]);
    u.x = u.x * alpha + beta * subx;
    u.y = u.y * alpha + beta * suby;
    *reinterpret_cast<float2*>(&U[uoff]) = u;
    if (lane == 0) { m_run[c] = m2; den_run[c] = den * alpha + beta; }
}

// ---- final: V = (U/den) @ Wv + bv, in-place on d_out -------------------

__global__ void final_gemm_kernel(float* __restrict__ U, const float* __restrict__ den_run,
                                  const float* __restrict__ Wv, const float* __restrict__ bv, int n) {
    __shared__ float M[8][DFEAT];
    int wid = threadIdx.x >> 6, lane = threadIdx.x & 63;
    int base = blockIdx.x * 8;
    for (int u = 0; u < 2; ++u) {
        int nn = base + wid * 2 + u;
        if (nn < n) {
            float inv = 1.0f / den_run[nn];
            float2 v = *reinterpret_cast<const float2*>(&U[(size_t)nn * DFEAT + lane * 2]);
            *reinterpret_cast<float2*>(&M[wid * 2 + u][lane * 2]) = make_float2(v.x * inv, v.y * inv);
        }
    }
    __syncthreads();
    int j = threadIdx.x & 127, hgrp = threadIdx.x >> 7;
    float bvj = bv[j];
    float acc0 = bvj, acc1 = bvj, acc2 = bvj, acc3 = bvj;
    for (int d = 0; d < DFEAT; ++d) {
        float w = Wv[d * DFEAT + j];
        acc0 += M[hgrp * 4 + 0][d] * w;
        acc1 += M[hgrp * 4 + 1][d] * w;
        acc2 += M[hgrp * 4 + 2][d] * w;
        acc3 += M[hgrp * 4 + 3][d] * w;
    }
    int n0 = base + hgrp * 4;
    if (n0 + 0 < n) U[(size_t)(n0 + 0) * DFEAT + j] = acc0;
    if (n0 + 1 < n) U[(size_t)(n0 + 1) * DFEAT + j] = acc1;
    if (n0 + 2 < n) U[(size_t)(n0 + 2) * DFEAT + j] = acc2;
    if (n0 + 3 < n) U[(size_t)(n0 + 3) * DFEAT + j] = acc3;
}

// ------------------------------------------------------------------------

extern "C" void kernel_launch(void* const* d_in, const int* in_sizes, int n_in,
                              void* d_out, int out_size, void* d_ws, size_t ws_size,
                              hipStream_t stream) {
    const float* h_train = (const float*)d_in[0];
    const float* h_ori   = (const float*)d_in[1];
    const int*   eidx    = (const int*)d_in[2];
    const float* Wq = (const float*)d_in[3];
    const float* bq = (const float*)d_in[4];
    const float* Wk = (const float*)d_in[5];
    const float* bk = (const float*)d_in[6];
    const float* Wv = (const float*)d_in[7];
    const float* bv = (const float*)d_in[8];
    float* out = (float*)d_out;   // doubles as U accumulator

    const int n = in_sizes[0] / DFEAT;   // 100000
    const int E = in_sizes[2] / 2;       // 1600000
    const int nchunks = (n + CHUNK - 1) / CHUNK;
    const int NPART = 512;
    size_t ND = (size_t)n * DFEAT;

    // workspace carve (~112 MB)
    char* p = (char*)d_ws;
    auto alloc = [&](size_t bytes) { char* r = p; p += align256(bytes); return r; };
    float*    bufA     = (float*)   alloc(ND * sizeof(float));
    float*    bufB     = (float*)   alloc(ND * sizeof(float));
    int*      rowlist  = (int*)     alloc((size_t)E * 4);
    float*    dinv     = (float*)   alloc((size_t)n * 4);
    unsigned* cnt_row  = (unsigned*)alloc((size_t)n * 4);
    unsigned* cnt_col  = (unsigned*)alloc((size_t)n * 4);
    unsigned* colptr   = (unsigned*)alloc((size_t)(n + 1) * 4);
    unsigned* cursor   = (unsigned*)alloc((size_t)n * 4);
    float*    m_run    = (float*)   alloc((size_t)n * 4);
    float*    den_run  = (float*)   alloc((size_t)n * 4);
    unsigned* chunksum = (unsigned*)alloc((size_t)nchunks * 4);
    unsigned* chunkoff = (unsigned*)alloc((size_t)(nchunks + 1) * 4);
    float*    partial  = (float*)   alloc((size_t)NPART * DFEAT * 4);
    float*    wkq_ck   = (float*)   alloc((DFEAT + 1) * 4);
    if ((size_t)(p - (char*)d_ws) > ws_size) return;  // ws too small: fail loud (absmax), not a crash

    hipMemsetAsync(cnt_row, 0, (size_t)n * 4, stream);
    hipMemsetAsync(cnt_col, 0, (size_t)n * 4, stream);

    count_kernel<<<(E + 255) / 256, 256, 0, stream>>>(eidx, cnt_row, cnt_col, E);
    dinv_kernel<<<(n + 255) / 256, 256, 0, stream>>>(cnt_row, dinv, n);
    chunk_reduce_kernel<<<nchunks, 256, 0, stream>>>(cnt_col, chunksum, n);
    scan_chunks_kernel<<<1, 64, 0, stream>>>(chunksum, chunkoff, colptr, nchunks, n, E);
    chunk_scan_kernel<<<nchunks, 256, 0, stream>>>(cnt_col, chunkoff, colptr, n);
    copy_u32_kernel<<<(n + 255) / 256, 256, 0, stream>>>(colptr, cursor, n);
    fill_csc_kernel<<<(E + 255) / 256, 256, 0, stream>>>(eidx, cursor, rowlist, E);

    colmean_partial_kernel<<<NPART, 256, 0, stream>>>(h_ori, partial, n);
    wkq_kernel<<<1, 128, 0, stream>>>(partial, NPART, Wq, bq, Wk, bk, wkq_ck, 1.0f / (float)n);

    // hop 0: a_feat (k=0) + x1 (k=1), init online-softmax state; x1 -> bufA
    prop0_kernel<<<(n + 3) / 4, 256, 0, stream>>>(h_train, rowlist, colptr, dinv, wkq_ck,
                                                  bufA, out, m_run, den_run, n);
    // hops 2..7: x_t -> ping-pong, update {m, den, U}
    float* xin = bufA; float* xout = bufB;
    for (int t = 2; t <= 7; ++t) {
        prop_fused_kernel<<<(n + 3) / 4, 256, 0, stream>>>(xin, rowlist, colptr, dinv, wkq_ck,
                                                           xout, out, m_run, den_run, n);
        float* tmp = xin; xin = xout; xout = tmp;
    }

    final_gemm_kernel<<<(n + 7) / 8, 256, 0, stream>>>(out, den_run, Wv, bv, n);
}

// Round 3
// 1230.834 us; speedup vs baseline: 1.2094x; 1.2094x over previous
//
#include <hip/hip_runtime.h>
#include <hip/hip_fp16.h>
#include <hip/hip_bf16.h>
#include <math.h>

#define DFEAT 128
#define QKD 32
#define CHUNK 2048
#define BW 64            // CSC bucket width (columns per bucket)

static inline size_t align256(size_t x) { return (x + 255) & ~size_t(255); }

// ---- degree / CSC build ------------------------------------------------

__global__ void count_kernel(const int* __restrict__ eidx, unsigned* __restrict__ cnt_row,
                             unsigned* __restrict__ cnt_col, int E) {
    int e = blockIdx.x * blockDim.x + threadIdx.x;
    if (e < E) {
        atomicAdd(&cnt_row[eidx[e]], 1u);       // deg over row (source)
        atomicAdd(&cnt_col[eidx[E + e]], 1u);   // CSC histogram over col (dest)
    }
}

// dinv = deg^-1/2 ; dinv2 = 1/deg ; rec = deg^1/2
__global__ void dinv_kernel(const unsigned* __restrict__ cnt_row, float* __restrict__ dinv,
                            float* __restrict__ dinv2, float* __restrict__ rec, int n) {
    int i = blockIdx.x * blockDim.x + threadIdx.x;
    if (i < n) {
        unsigned c = cnt_row[i];
        if (c < 1u) c = 1u;
        float fd = (float)c;
        float sq = sqrtf(fd);
        dinv[i] = 1.0f / sq;
        dinv2[i] = 1.0f / fd;
        rec[i] = sq;
    }
}

__global__ void chunk_reduce_kernel(const unsigned* __restrict__ cnt, unsigned* __restrict__ chunksum, int n) {
    __shared__ unsigned s[256];
    int base = blockIdx.x * CHUNK;
    unsigned acc = 0;
    for (int i = threadIdx.x; i < CHUNK; i += 256) {
        int g = base + i;
        if (g < n) acc += cnt[g];
    }
    s[threadIdx.x] = acc; __syncthreads();
    for (int off = 128; off > 0; off >>= 1) {
        if (threadIdx.x < off) s[threadIdx.x] += s[threadIdx.x + off];
        __syncthreads();
    }
    if (threadIdx.x == 0) chunksum[blockIdx.x] = s[0];
}

__global__ void scan_chunks_kernel(const unsigned* __restrict__ chunksum, unsigned* __restrict__ chunkoff,
                                   unsigned* __restrict__ colptr, int nchunks, int n, int E) {
    if (threadIdx.x == 0 && blockIdx.x == 0) {
        unsigned acc = 0;
        for (int i = 0; i < nchunks; ++i) { chunkoff[i] = acc; acc += chunksum[i]; }
        colptr[n] = (unsigned)E;
    }
}

__global__ void chunk_scan_kernel(const unsigned* __restrict__ cnt, const unsigned* __restrict__ chunkoff,
                                  unsigned* __restrict__ colptr, int n) {
    __shared__ unsigned s[256];
    int base = blockIdx.x * CHUNK + threadIdx.x * 8;
    unsigned v[8]; unsigned acc = 0;
#pragma unroll
    for (int j = 0; j < 8; ++j) { int g = base + j; v[j] = (g < n) ? cnt[g] : 0u; acc += v[j]; }
    s[threadIdx.x] = acc; __syncthreads();
    for (int off = 1; off < 256; off <<= 1) {
        unsigned t = (threadIdx.x >= (unsigned)off) ? s[threadIdx.x - off] : 0u;
        __syncthreads();
        s[threadIdx.x] += t;
        __syncthreads();
    }
    unsigned prefix = chunkoff[blockIdx.x] + s[threadIdx.x] - acc;  // exclusive
#pragma unroll
    for (int j = 0; j < 8; ++j) { int g = base + j; if (g < n) colptr[g] = prefix; prefix += v[j]; }
}

__global__ void bcur_init_kernel(const unsigned* __restrict__ colptr, unsigned* __restrict__ bcur,
                                 int NB, int n) {
    int b = blockIdx.x * blockDim.x + threadIdx.x;
    if (b < NB) {
        int c = b * BW; if (c > n) c = n;
        bcur[b] = colptr[c];
    }
}

// Pass A: scatter packed (row<<6 | col%64) into bucket regions (CSC order at
// bucket granularity, since cursors start at colptr[bucket_base]).
__global__ void scatterA_kernel(const int* __restrict__ eidx, unsigned* __restrict__ bcur,
                                unsigned* __restrict__ pairs, int E) {
    int e = blockIdx.x * blockDim.x + threadIdx.x;
    if (e < E) {
        int row = eidx[e];
        int col = eidx[E + e];
        int b = col >> 6;
        unsigned p = atomicAdd(&bcur[b], 1u);
        pairs[p] = ((unsigned)row << 6) | (unsigned)(col & 63);
    }
}

// Pass B: one block per bucket; LDS cursors resolve exact CSC positions.
// Writes land in a ~4KB contiguous window per block.
__global__ void fillB_kernel(const unsigned* __restrict__ pairs, const unsigned* __restrict__ colptr,
                             int* __restrict__ rowlist, int n) {
    __shared__ unsigned cur[BW];
    int base = blockIdx.x * BW;
    int t = threadIdx.x;
    if (t < BW) { int c = base + t; cur[t] = (c < n) ? colptr[c] : 0u; }
    __syncthreads();
    int hi = base + BW; if (hi > n) hi = n;
    unsigned beg = colptr[base], end = colptr[hi];
    for (unsigned e = beg + t; e < end; e += 256) {
        unsigned pk = pairs[e];
        unsigned pos = atomicAdd(&cur[pk & 63u], 1u);
        rowlist[pos] = (int)(pk >> 6);
    }
}

// ---- y0 = fp16(dinv * h_train) ----------------------------------------

__global__ void scale_cvt_kernel(const float* __restrict__ h, const float* __restrict__ dinv,
                                 __half2* __restrict__ y, int n64) {
    int i = blockIdx.x * blockDim.x + threadIdx.x;
    if (i < n64) {
        float d = dinv[i >> 6];
        float2 v = reinterpret_cast<const float2*>(h)[i];
        y[i] = __floats2half2_rn(d * v.x, d * v.y);
    }
}

// ---- query path (atomic-free, two stage) -------------------------------

__global__ void colmean_partial_kernel(const float* __restrict__ h, float* __restrict__ partial, int n) {
    __shared__ float s[256];
    int t = threadIdx.x;
    int col = t & 127;
    int half = t >> 7;
    float acc = 0.f;
    for (int r = blockIdx.x * 2 + half; r < n; r += gridDim.x * 2)
        acc += h[(size_t)r * DFEAT + col];
    s[t] = acc; __syncthreads();
    if (t < 128) partial[(size_t)blockIdx.x * DFEAT + t] = s[t] + s[t + 128];
}

__global__ void wkq_kernel(const float* __restrict__ partial, int nparts,
                           const float* __restrict__ Wq, const float* __restrict__ bq,
                           const float* __restrict__ Wk, const float* __restrict__ bk,
                           float* __restrict__ wkq_ck, float inv_n) {
    __shared__ float hb[DFEAT];
    __shared__ float qg[QKD];
    int t = threadIdx.x;  // 128 threads
    float acc = 0.f;
    for (int b = 0; b < nparts; ++b) acc += partial[(size_t)b * DFEAT + t];
    hb[t] = acc * inv_n;
    __syncthreads();
    if (t < QKD) {
        float a = bq[t];
        for (int d = 0; d < DFEAT; ++d) a += hb[d] * Wq[d * QKD + t];
        qg[t] = a;
    }
    __syncthreads();
    float w = 0.f;
    for (int q = 0; q < QKD; ++q) w += Wk[t * QKD + q] * qg[q];
    wkq_ck[t] = w;
    if (t == 0) {
        float c = 0.f;
        for (int q = 0; q < QKD; ++q) c += bk[q] * qg[q];
        wkq_ck[DFEAT] = c;
    }
}

// ---- propagate (y-space, fp16) + online softmax ------------------------
// y = dinv*x stored fp16. S_c = sum_{in-edges} y[r].
// x' = x - dinv[c]*S  ->  y' = y - dinv2[c]*S ;  x' = rec[c]*y'.
// wave per dest node, half2 per lane (256B coalesced row gathers).

__device__ __forceinline__ float wave_score2(float px, float py, float wx, float wy,
                                             float ck, float scale) {
    float s = px * wx + py * wy;
#pragma unroll
    for (int off = 32; off > 0; off >>= 1) s += __shfl_xor(s, off, 64);
    return (s + ck) * scale;
}

__device__ __forceinline__ void gather_sum(const __half2* __restrict__ y,
                                           const int* __restrict__ rowlist,
                                           unsigned beg, unsigned end, int lane,
                                           float& ax, float& ay) {
    unsigned e = beg;
    for (; e + 8 <= end; e += 8) {
        int r0 = rowlist[e], r1 = rowlist[e+1], r2 = rowlist[e+2], r3 = rowlist[e+3];
        int r4 = rowlist[e+4], r5 = rowlist[e+5], r6 = rowlist[e+6], r7 = rowlist[e+7];
        __half2 v0 = y[(size_t)r0 * 64 + lane];
        __half2 v1 = y[(size_t)r1 * 64 + lane];
        __half2 v2 = y[(size_t)r2 * 64 + lane];
        __half2 v3 = y[(size_t)r3 * 64 + lane];
        __half2 v4 = y[(size_t)r4 * 64 + lane];
        __half2 v5 = y[(size_t)r5 * 64 + lane];
        __half2 v6 = y[(size_t)r6 * 64 + lane];
        __half2 v7 = y[(size_t)r7 * 64 + lane];
        float2 f0 = __half22float2(v0), f1 = __half22float2(v1);
        float2 f2 = __half22float2(v2), f3 = __half22float2(v3);
        float2 f4 = __half22float2(v4), f5 = __half22float2(v5);
        float2 f6 = __half22float2(v6), f7 = __half22float2(v7);
        ax += (f0.x + f1.x) + (f2.x + f3.x) + (f4.x + f5.x) + (f6.x + f7.x);
        ay += (f0.y + f1.y) + (f2.y + f3.y) + (f4.y + f5.y) + (f6.y + f7.y);
    }
    for (; e < end; ++e) {
        float2 f = __half22float2(y[(size_t)rowlist[e] * 64 + lane]);
        ax += f.x; ay += f.y;
    }
}

// hop0: a_feat = x0 + dinv*S (k=0), x1 = x0 - dinv*S (k=1). Init {m,den,U}.
__global__ void prop0_kernel(const float* __restrict__ x0, const __half2* __restrict__ y0,
                             const int* __restrict__ rowlist, const unsigned* __restrict__ colptr,
                             const float* __restrict__ dinv, const float* __restrict__ wkq_ck,
                             __half2* __restrict__ yout, __half2* __restrict__ U,
                             float* __restrict__ m_run, float* __restrict__ den_run, int n) {
    int wid = threadIdx.x >> 6;
    int lane = threadIdx.x & 63;
    int c = blockIdx.x * 4 + wid;
    if (c >= n) return;
    unsigned beg = colptr[c], end = colptr[c + 1];
    float ax = 0.f, ay = 0.f;
    gather_sum(y0, rowlist, beg, end, lane, ax, ay);
    float dc = dinv[c];
    float2 b = *reinterpret_cast<const float2*>(&x0[(size_t)c * DFEAT + lane * 2]);
    float px = dc * ax, py = dc * ay;
    float addx = b.x + px, addy = b.y + py;
    float subx = b.x - px, suby = b.y - py;
    yout[(size_t)c * 64 + lane] = __floats2half2_rn(dc * subx, dc * suby);

    const float scale = 0.08838834764831845f;  // 1/sqrt(128)
    float ck = wkq_ck[DFEAT];
    float2 wk2 = *reinterpret_cast<const float2*>(&wkq_ck[lane * 2]);
    float s0 = wave_score2(addx, addy, wk2.x, wk2.y, ck, scale);
    float s1 = wave_score2(subx, suby, wk2.x, wk2.y, ck, scale);
    float m = fmaxf(s0, s1);
    float e0 = expf(s0 - m), e1 = expf(s1 - m);
    float ux = e0 * addx + e1 * subx;
    float uy = e0 * addy + e1 * suby;
    U[(size_t)c * 64 + lane] = __floats2half2_rn(ux, uy);
    if (lane == 0) { m_run[c] = m; den_run[c] = e0 + e1; }
}

// hops 2..7: y' = y - dinv2*S ; x' = rec*y' ; flash update {m,den,U}.
__global__ void prop_fused_kernel(const __half2* __restrict__ y, const int* __restrict__ rowlist,
                                  const unsigned* __restrict__ colptr,
                                  const float* __restrict__ dinv2, const float* __restrict__ rec,
                                  const float* __restrict__ wkq_ck,
                                  __half2* __restrict__ yout, __half2* __restrict__ U,
                                  float* __restrict__ m_run, float* __restrict__ den_run, int n) {
    int wid = threadIdx.x >> 6;
    int lane = threadIdx.x & 63;
    int c = blockIdx.x * 4 + wid;
    if (c >= n) return;
    unsigned beg = colptr[c], end = colptr[c + 1];
    float ax = 0.f, ay = 0.f;
    gather_sum(y, rowlist, beg, end, lane, ax, ay);
    float d2 = dinv2[c], rc = rec[c];
    float2 b = __half22float2(y[(size_t)c * 64 + lane]);
    float ypx = b.x - d2 * ax, ypy = b.y - d2 * ay;
    yout[(size_t)c * 64 + lane] = __floats2half2_rn(ypx, ypy);
    float xx = rc * ypx, xy = rc * ypy;

    const float scale = 0.08838834764831845f;
    float ck = wkq_ck[DFEAT];
    float2 wk2 = *reinterpret_cast<const float2*>(&wkq_ck[lane * 2]);
    float s = wave_score2(xx, xy, wk2.x, wk2.y, ck, scale);
    float m = m_run[c], den = den_run[c];
    float m2 = fmaxf(m, s);
    float alpha = expf(m - m2), beta = expf(s - m2);
    size_t uoff = (size_t)c * 64 + lane;
    float2 u = __half22float2(U[uoff]);
    u.x = u.x * alpha + beta * xx;
    u.y = u.y * alpha + beta * xy;
    U[uoff] = __floats2half2_rn(u.x, u.y);
    if (lane == 0) { m_run[c] = m2; den_run[c] = den * alpha + beta; }
}

// ---- final: V = (U/den) @ Wv + bv -> d_out ----------------------------

__global__ void final_gemm_kernel(const __half2* __restrict__ U, const float* __restrict__ den_run,
                                  const float* __restrict__ Wv, const float* __restrict__ bv,
                                  float* __restrict__ out, int n) {
    __shared__ float M[8][DFEAT];
    int wid = threadIdx.x >> 6, lane = threadIdx.x & 63;
    int base = blockIdx.x * 8;
    for (int u = 0; u < 2; ++u) {
        int nn = base + wid * 2 + u;
        if (nn < n) {
            float inv = 1.0f / den_run[nn];
            float2 v = __half22float2(U[(size_t)nn * 64 + lane]);
            *reinterpret_cast<float2*>(&M[wid * 2 + u][lane * 2]) = make_float2(v.x * inv, v.y * inv);
        }
    }
    __syncthreads();
    int j = threadIdx.x & 127, hgrp = threadIdx.x >> 7;
    float bvj = bv[j];
    float acc0 = bvj, acc1 = bvj, acc2 = bvj, acc3 = bvj;
    for (int d = 0; d < DFEAT; ++d) {
        float w = Wv[d * DFEAT + j];
        acc0 += M[hgrp * 4 + 0][d] * w;
        acc1 += M[hgrp * 4 + 1][d] * w;
        acc2 += M[hgrp * 4 + 2][d] * w;
        acc3 += M[hgrp * 4 + 3][d] * w;
    }
    int n0 = base + hgrp * 4;
    if (n0 + 0 < n) out[(size_t)(n0 + 0) * DFEAT + j] = acc0;
    if (n0 + 1 < n) out[(size_t)(n0 + 1) * DFEAT + j] = acc1;
    if (n0 + 2 < n) out[(size_t)(n0 + 2) * DFEAT + j] = acc2;
    if (n0 + 3 < n) out[(size_t)(n0 + 3) * DFEAT + j] = acc3;
}

// ------------------------------------------------------------------------

extern "C" void kernel_launch(void* const* d_in, const int* in_sizes, int n_in,
                              void* d_out, int out_size, void* d_ws, size_t ws_size,
                              hipStream_t stream) {
    const float* h_train = (const float*)d_in[0];
    const float* h_ori   = (const float*)d_in[1];
    const int*   eidx    = (const int*)d_in[2];
    const float* Wq = (const float*)d_in[3];
    const float* bq = (const float*)d_in[4];
    const float* Wk = (const float*)d_in[5];
    const float* bk = (const float*)d_in[6];
    const float* Wv = (const float*)d_in[7];
    const float* bv = (const float*)d_in[8];
    float* out = (float*)d_out;

    const int n = in_sizes[0] / DFEAT;   // 100000
    const int E = in_sizes[2] / 2;       // 1600000
    const int nchunks = (n + CHUNK - 1) / CHUNK;
    const int NB = (n + BW - 1) / BW;    // buckets
    const int NPART = 512;
    size_t ND2 = (size_t)n * 64;         // half2 elements per feature buffer

    // workspace carve (~95 MB)
    char* p = (char*)d_ws;
    auto alloc = [&](size_t bytes) { char* r = p; p += align256(bytes); return r; };
    __half2*  yA       = (__half2*) alloc(ND2 * 4);
    __half2*  yB       = (__half2*) alloc(ND2 * 4);
    __half2*  U16      = (__half2*) alloc(ND2 * 4);
    int*      rowlist  = (int*)     alloc((size_t)E * 4);
    unsigned* pairs    = (unsigned*)alloc((size_t)E * 4);
    float*    dinv     = (float*)   alloc((size_t)n * 4);
    float*    dinv2    = (float*)   alloc((size_t)n * 4);
    float*    rec      = (float*)   alloc((size_t)n * 4);
    unsigned* cnt_row  = (unsigned*)alloc((size_t)n * 4);
    unsigned* cnt_col  = (unsigned*)alloc((size_t)n * 4);
    unsigned* colptr   = (unsigned*)alloc((size_t)(n + 1) * 4);
    unsigned* bcur     = (unsigned*)alloc((size_t)NB * 4);
    float*    m_run    = (float*)   alloc((size_t)n * 4);
    float*    den_run  = (float*)   alloc((size_t)n * 4);
    unsigned* chunksum = (unsigned*)alloc((size_t)nchunks * 4);
    unsigned* chunkoff = (unsigned*)alloc((size_t)(nchunks + 1) * 4);
    float*    partial  = (float*)   alloc((size_t)NPART * DFEAT * 4);
    float*    wkq_ck   = (float*)   alloc((DFEAT + 1) * 4);
    if ((size_t)(p - (char*)d_ws) > ws_size) return;  // fail loud, not a crash

    hipMemsetAsync(cnt_row, 0, (size_t)n * 4, stream);
    hipMemsetAsync(cnt_col, 0, (size_t)n * 4, stream);

    count_kernel<<<(E + 255) / 256, 256, 0, stream>>>(eidx, cnt_row, cnt_col, E);
    dinv_kernel<<<(n + 255) / 256, 256, 0, stream>>>(cnt_row, dinv, dinv2, rec, n);
    chunk_reduce_kernel<<<nchunks, 256, 0, stream>>>(cnt_col, chunksum, n);
    scan_chunks_kernel<<<1, 64, 0, stream>>>(chunksum, chunkoff, colptr, nchunks, n, E);
    chunk_scan_kernel<<<nchunks, 256, 0, stream>>>(cnt_col, chunkoff, colptr, n);
    bcur_init_kernel<<<(NB + 255) / 256, 256, 0, stream>>>(colptr, bcur, NB, n);
    scatterA_kernel<<<(E + 255) / 256, 256, 0, stream>>>(eidx, bcur, pairs, E);
    fillB_kernel<<<NB, 256, 0, stream>>>(pairs, colptr, rowlist, n);

    scale_cvt_kernel<<<(n * 64 + 255) / 256, 256, 0, stream>>>(h_train, dinv, yA, n * 64);

    colmean_partial_kernel<<<NPART, 256, 0, stream>>>(h_ori, partial, n);
    wkq_kernel<<<1, 128, 0, stream>>>(partial, NPART, Wq, bq, Wk, bk, wkq_ck, 1.0f / (float)n);

    // hop 0: uses h_train (f32 center row) + yA (fp16 gather); y1 -> yB
    prop0_kernel<<<(n + 3) / 4, 256, 0, stream>>>(h_train, yA, rowlist, colptr, dinv, wkq_ck,
                                                  yB, U16, m_run, den_run, n);
    // hops 2..7: ping-pong yB <-> yA
    __half2* xin = yB; __half2* xout = yA;
    for (int t = 2; t <= 7; ++t) {
        prop_fused_kernel<<<(n + 3) / 4, 256, 0, stream>>>(xin, rowlist, colptr, dinv2, rec, wkq_ck,
                                                           xout, U16, m_run, den_run, n);
        __half2* tmp = xin; xin = xout; xout = tmp;
    }

    final_gemm_kernel<<<(n + 7) / 8, 256, 0, stream>>>(U16, den_run, Wv, bv, out, n);
}

// Round 4
// 1052.138 us; speedup vs baseline: 1.4148x; 1.1698x over previous
//
#include <hip/hip_runtime.h>
#include <hip/hip_fp16.h>
#include <math.h>

#define DFEAT 128
#define QKD 32
#define CHUNK 2048

static inline size_t align256(size_t x) { return (x + 255) & ~size_t(255); }

// ---- degree / CSC build ------------------------------------------------

__global__ void count_kernel(const int* __restrict__ eidx, unsigned* __restrict__ cnt_row,
                             unsigned* __restrict__ cnt_col, int E) {
    int e = blockIdx.x * blockDim.x + threadIdx.x;
    if (e < E) {
        atomicAdd(&cnt_row[eidx[e]], 1u);       // deg over row (source)
        atomicAdd(&cnt_col[eidx[E + e]], 1u);   // CSC histogram over col (dest)
    }
}

// dinv = deg^-1/2 ; dinv2 = 1/deg ; rec = deg^1/2
__global__ void dinv_kernel(const unsigned* __restrict__ cnt_row, float* __restrict__ dinv,
                            float* __restrict__ dinv2, float* __restrict__ rec, int n) {
    int i = blockIdx.x * blockDim.x + threadIdx.x;
    if (i < n) {
        unsigned c = cnt_row[i];
        if (c < 1u) c = 1u;
        float fd = (float)c;
        float sq = sqrtf(fd);
        dinv[i] = 1.0f / sq;
        dinv2[i] = 1.0f / fd;
        rec[i] = sq;
    }
}

__global__ void chunk_reduce_kernel(const unsigned* __restrict__ cnt, unsigned* __restrict__ chunksum, int n) {
    __shared__ unsigned s[256];
    int base = blockIdx.x * CHUNK;
    unsigned acc = 0;
    for (int i = threadIdx.x; i < CHUNK; i += 256) {
        int g = base + i;
        if (g < n) acc += cnt[g];
    }
    s[threadIdx.x] = acc; __syncthreads();
    for (int off = 128; off > 0; off >>= 1) {
        if (threadIdx.x < off) s[threadIdx.x] += s[threadIdx.x + off];
        __syncthreads();
    }
    if (threadIdx.x == 0) chunksum[blockIdx.x] = s[0];
}

__global__ void scan_chunks_kernel(const unsigned* __restrict__ chunksum, unsigned* __restrict__ chunkoff,
                                   unsigned* __restrict__ colptr, int nchunks, int n, int E) {
    if (threadIdx.x == 0 && blockIdx.x == 0) {
        unsigned acc = 0;
        for (int i = 0; i < nchunks; ++i) { chunkoff[i] = acc; acc += chunksum[i]; }
        colptr[n] = (unsigned)E;
    }
}

// writes colptr AND cursor (saves the copy kernel)
__global__ void chunk_scan_kernel(const unsigned* __restrict__ cnt, const unsigned* __restrict__ chunkoff,
                                  unsigned* __restrict__ colptr, unsigned* __restrict__ cursor, int n) {
    __shared__ unsigned s[256];
    int base = blockIdx.x * CHUNK + threadIdx.x * 8;
    unsigned v[8]; unsigned acc = 0;
#pragma unroll
    for (int j = 0; j < 8; ++j) { int g = base + j; v[j] = (g < n) ? cnt[g] : 0u; acc += v[j]; }
    s[threadIdx.x] = acc; __syncthreads();
    for (int off = 1; off < 256; off <<= 1) {
        unsigned t = (threadIdx.x >= (unsigned)off) ? s[threadIdx.x - off] : 0u;
        __syncthreads();
        s[threadIdx.x] += t;
        __syncthreads();
    }
    unsigned prefix = chunkoff[blockIdx.x] + s[threadIdx.x] - acc;  // exclusive
#pragma unroll
    for (int j = 0; j < 8; ++j) {
        int g = base + j;
        if (g < n) { colptr[g] = prefix; cursor[g] = prefix; }
        prefix += v[j];
    }
}

__global__ void fill_csc_kernel(const int* __restrict__ eidx, unsigned* __restrict__ cursor,
                                int* __restrict__ rowlist, int E) {
    int e = blockIdx.x * blockDim.x + threadIdx.x;
    if (e < E) {
        int c = eidx[E + e];
        unsigned p = atomicAdd(&cursor[c], 1u);
        rowlist[p] = eidx[e];
    }
}

// ---- y0 = fp16(dinv * h_train) ----------------------------------------

__global__ void scale_cvt_kernel(const float* __restrict__ h, const float* __restrict__ dinv,
                                 __half2* __restrict__ y, int n64) {
    int i = blockIdx.x * blockDim.x + threadIdx.x;
    if (i < n64) {
        float d = dinv[i >> 6];
        float2 v = reinterpret_cast<const float2*>(h)[i];
        y[i] = __floats2half2_rn(d * v.x, d * v.y);
    }
}

// ---- query path (atomic-free, two stage) -------------------------------

__global__ void colmean_partial_kernel(const float* __restrict__ h, float* __restrict__ partial, int n) {
    __shared__ float s[256];
    int t = threadIdx.x;
    int col = t & 127;
    int half = t >> 7;
    float acc = 0.f;
    for (int r = blockIdx.x * 2 + half; r < n; r += gridDim.x * 2)
        acc += h[(size_t)r * DFEAT + col];
    s[t] = acc; __syncthreads();
    if (t < 128) partial[(size_t)blockIdx.x * DFEAT + t] = s[t] + s[t + 128];
}

__global__ void wkq_kernel(const float* __restrict__ partial, int nparts,
                           const float* __restrict__ Wq, const float* __restrict__ bq,
                           const float* __restrict__ Wk, const float* __restrict__ bk,
                           float* __restrict__ wkq_ck, float inv_n) {
    __shared__ float hb[DFEAT];
    __shared__ float qg[QKD];
    int t = threadIdx.x;  // 128 threads
    float acc = 0.f;
    for (int b = 0; b < nparts; ++b) acc += partial[(size_t)b * DFEAT + t];
    hb[t] = acc * inv_n;
    __syncthreads();
    if (t < QKD) {
        float a = bq[t];
        for (int d = 0; d < DFEAT; ++d) a += hb[d] * Wq[d * QKD + t];
        qg[t] = a;
    }
    __syncthreads();
    float w = 0.f;
    for (int q = 0; q < QKD; ++q) w += Wk[t * QKD + q] * qg[q];
    wkq_ck[t] = w;
    if (t == 0) {
        float c = 0.f;
        for (int q = 0; q < QKD; ++q) c += bk[q] * qg[q];
        wkq_ck[DFEAT] = c;
    }
}

// ---- propagate (y-space, fp16) + online softmax ------------------------
// y = dinv*x stored fp16. S_c = sum_{in-edges} y[r].
// y' = y - dinv2[c]*S ;  x' = rec[c]*y'.
// wave per dest node, half2 per lane (256B coalesced row gathers).
// 16-wide gather unroll; rowlist read as wave-uniform int4 (broadcast).

__device__ __forceinline__ float wave_score2(float px, float py, float wx, float wy,
                                             float ck, float scale) {
    float s = px * wx + py * wy;
#pragma unroll
    for (int off = 32; off > 0; off >>= 1) s += __shfl_xor(s, off, 64);
    return (s + ck) * scale;
}

__device__ __forceinline__ void gather_sum(const __half2* __restrict__ y,
                                           const int* __restrict__ rowlist,
                                           unsigned beg, unsigned end, int lane,
                                           float& ax, float& ay) {
    unsigned e = beg;
    for (; e + 16 <= end; e += 16) {
        int4 q0 = *reinterpret_cast<const int4*>(&rowlist[e]);
        int4 q1 = *reinterpret_cast<const int4*>(&rowlist[e + 4]);
        int4 q2 = *reinterpret_cast<const int4*>(&rowlist[e + 8]);
        int4 q3 = *reinterpret_cast<const int4*>(&rowlist[e + 12]);
        __half2 v0  = y[(size_t)q0.x * 64 + lane];
        __half2 v1  = y[(size_t)q0.y * 64 + lane];
        __half2 v2  = y[(size_t)q0.z * 64 + lane];
        __half2 v3  = y[(size_t)q0.w * 64 + lane];
        __half2 v4  = y[(size_t)q1.x * 64 + lane];
        __half2 v5  = y[(size_t)q1.y * 64 + lane];
        __half2 v6  = y[(size_t)q1.z * 64 + lane];
        __half2 v7  = y[(size_t)q1.w * 64 + lane];
        __half2 v8  = y[(size_t)q2.x * 64 + lane];
        __half2 v9  = y[(size_t)q2.y * 64 + lane];
        __half2 v10 = y[(size_t)q2.z * 64 + lane];
        __half2 v11 = y[(size_t)q2.w * 64 + lane];
        __half2 v12 = y[(size_t)q3.x * 64 + lane];
        __half2 v13 = y[(size_t)q3.y * 64 + lane];
        __half2 v14 = y[(size_t)q3.z * 64 + lane];
        __half2 v15 = y[(size_t)q3.w * 64 + lane];
        float2 f0 = __half22float2(v0),  f1 = __half22float2(v1);
        float2 f2 = __half22float2(v2),  f3 = __half22float2(v3);
        float2 f4 = __half22float2(v4),  f5 = __half22float2(v5);
        float2 f6 = __half22float2(v6),  f7 = __half22float2(v7);
        float2 f8 = __half22float2(v8),  f9 = __half22float2(v9);
        float2 f10 = __half22float2(v10), f11 = __half22float2(v11);
        float2 f12 = __half22float2(v12), f13 = __half22float2(v13);
        float2 f14 = __half22float2(v14), f15 = __half22float2(v15);
        ax += ((f0.x + f1.x) + (f2.x + f3.x)) + ((f4.x + f5.x) + (f6.x + f7.x))
            + ((f8.x + f9.x) + (f10.x + f11.x)) + ((f12.x + f13.x) + (f14.x + f15.x));
        ay += ((f0.y + f1.y) + (f2.y + f3.y)) + ((f4.y + f5.y) + (f6.y + f7.y))
            + ((f8.y + f9.y) + (f10.y + f11.y)) + ((f12.y + f13.y) + (f14.y + f15.y));
    }
    for (; e + 4 <= end; e += 4) {
        int4 q = *reinterpret_cast<const int4*>(&rowlist[e]);
        float2 f0 = __half22float2(y[(size_t)q.x * 64 + lane]);
        float2 f1 = __half22float2(y[(size_t)q.y * 64 + lane]);
        float2 f2 = __half22float2(y[(size_t)q.z * 64 + lane]);
        float2 f3 = __half22float2(y[(size_t)q.w * 64 + lane]);
        ax += (f0.x + f1.x) + (f2.x + f3.x);
        ay += (f0.y + f1.y) + (f2.y + f3.y);
    }
    for (; e < end; ++e) {
        float2 f = __half22float2(y[(size_t)rowlist[e] * 64 + lane]);
        ax += f.x; ay += f.y;
    }
}

// hop0: a_feat = x0 + dinv*S (k=0), x1 = x0 - dinv*S (k=1). Init {m,den,U}.
// center row x0 = rec[c]*y0[c].
__global__ void prop0_kernel(const __half2* __restrict__ y0,
                             const int* __restrict__ rowlist, const unsigned* __restrict__ colptr,
                             const float* __restrict__ dinv, const float* __restrict__ rec,
                             const float* __restrict__ wkq_ck,
                             __half2* __restrict__ yout, __half2* __restrict__ U,
                             float* __restrict__ m_run, float* __restrict__ den_run, int n) {
    int wid = threadIdx.x >> 6;
    int lane = threadIdx.x & 63;
    int c = blockIdx.x * 4 + wid;
    if (c >= n) return;
    unsigned beg = colptr[c], end = colptr[c + 1];
    float ax = 0.f, ay = 0.f;
    gather_sum(y0, rowlist, beg, end, lane, ax, ay);
    float dc = dinv[c], rc = rec[c];
    float2 b = __half22float2(y0[(size_t)c * 64 + lane]);
    float bx = rc * b.x, by = rc * b.y;          // x0 row
    float px = dc * ax, py = dc * ay;
    float addx = bx + px, addy = by + py;
    float subx = bx - px, suby = by - py;
    yout[(size_t)c * 64 + lane] = __floats2half2_rn(dc * subx, dc * suby);

    const float scale = 0.08838834764831845f;  // 1/sqrt(128)
    float ck = wkq_ck[DFEAT];
    float2 wk2 = *reinterpret_cast<const float2*>(&wkq_ck[lane * 2]);
    float s0 = wave_score2(addx, addy, wk2.x, wk2.y, ck, scale);
    float s1 = wave_score2(subx, suby, wk2.x, wk2.y, ck, scale);
    float m = fmaxf(s0, s1);
    float e0 = expf(s0 - m), e1 = expf(s1 - m);
    float ux = e0 * addx + e1 * subx;
    float uy = e0 * addy + e1 * suby;
    U[(size_t)c * 64 + lane] = __floats2half2_rn(ux, uy);
    if (lane == 0) { m_run[c] = m; den_run[c] = e0 + e1; }
}

// hops 2..7: y' = y - dinv2*S ; x' = rec*y' ; flash update {m,den,U}.
__global__ void prop_fused_kernel(const __half2* __restrict__ y, const int* __restrict__ rowlist,
                                  const unsigned* __restrict__ colptr,
                                  const float* __restrict__ dinv2, const float* __restrict__ rec,
                                  const float* __restrict__ wkq_ck,
                                  __half2* __restrict__ yout, __half2* __restrict__ U,
                                  float* __restrict__ m_run, float* __restrict__ den_run, int n) {
    int wid = threadIdx.x >> 6;
    int lane = threadIdx.x & 63;
    int c = blockIdx.x * 4 + wid;
    if (c >= n) return;
    unsigned beg = colptr[c], end = colptr[c + 1];
    float ax = 0.f, ay = 0.f;
    gather_sum(y, rowlist, beg, end, lane, ax, ay);
    float d2 = dinv2[c], rc = rec[c];
    float2 b = __half22float2(y[(size_t)c * 64 + lane]);
    float ypx = b.x - d2 * ax, ypy = b.y - d2 * ay;
    yout[(size_t)c * 64 + lane] = __floats2half2_rn(ypx, ypy);
    float xx = rc * ypx, xy = rc * ypy;

    const float scale = 0.08838834764831845f;
    float ck = wkq_ck[DFEAT];
    float2 wk2 = *reinterpret_cast<const float2*>(&wkq_ck[lane * 2]);
    float s = wave_score2(xx, xy, wk2.x, wk2.y, ck, scale);
    float m = m_run[c], den = den_run[c];
    float m2 = fmaxf(m, s);
    float alpha = expf(m - m2), beta = expf(s - m2);
    size_t uoff = (size_t)c * 64 + lane;
    float2 u = __half22float2(U[uoff]);
    u.x = u.x * alpha + beta * xx;
    u.y = u.y * alpha + beta * xy;
    U[uoff] = __floats2half2_rn(u.x, u.y);
    if (lane == 0) { m_run[c] = m2; den_run[c] = den * alpha + beta; }
}

// ---- final: V = (U/den) @ Wv + bv -> d_out ----------------------------

__global__ void final_gemm_kernel(const __half2* __restrict__ U, const float* __restrict__ den_run,
                                  const float* __restrict__ Wv, const float* __restrict__ bv,
                                  float* __restrict__ out, int n) {
    __shared__ float M[8][DFEAT];
    int wid = threadIdx.x >> 6, lane = threadIdx.x & 63;
    int base = blockIdx.x * 8;
    for (int u = 0; u < 2; ++u) {
        int nn = base + wid * 2 + u;
        if (nn < n) {
            float inv = 1.0f / den_run[nn];
            float2 v = __half22float2(U[(size_t)nn * 64 + lane]);
            *reinterpret_cast<float2*>(&M[wid * 2 + u][lane * 2]) = make_float2(v.x * inv, v.y * inv);
        }
    }
    __syncthreads();
    int j = threadIdx.x & 127, hgrp = threadIdx.x >> 7;
    float bvj = bv[j];
    float acc0 = bvj, acc1 = bvj, acc2 = bvj, acc3 = bvj;
    for (int d = 0; d < DFEAT; ++d) {
        float w = Wv[d * DFEAT + j];
        acc0 += M[hgrp * 4 + 0][d] * w;
        acc1 += M[hgrp * 4 + 1][d] * w;
        acc2 += M[hgrp * 4 + 2][d] * w;
        acc3 += M[hgrp * 4 + 3][d] * w;
    }
    int n0 = base + hgrp * 4;
    if (n0 + 0 < n) out[(size_t)(n0 + 0) * DFEAT + j] = acc0;
    if (n0 + 1 < n) out[(size_t)(n0 + 1) * DFEAT + j] = acc1;
    if (n0 + 2 < n) out[(size_t)(n0 + 2) * DFEAT + j] = acc2;
    if (n0 + 3 < n) out[(size_t)(n0 + 3) * DFEAT + j] = acc3;
}

// ------------------------------------------------------------------------

extern "C" void kernel_launch(void* const* d_in, const int* in_sizes, int n_in,
                              void* d_out, int out_size, void* d_ws, size_t ws_size,
                              hipStream_t stream) {
    const float* h_train = (const float*)d_in[0];
    const float* h_ori   = (const float*)d_in[1];
    const int*   eidx    = (const int*)d_in[2];
    const float* Wq = (const float*)d_in[3];
    const float* bq = (const float*)d_in[4];
    const float* Wk = (const float*)d_in[5];
    const float* bk = (const float*)d_in[6];
    const float* Wv = (const float*)d_in[7];
    const float* bv = (const float*)d_in[8];
    float* out = (float*)d_out;

    const int n = in_sizes[0] / DFEAT;   // 100000
    const int E = in_sizes[2] / 2;       // 1600000
    const int nchunks = (n + CHUNK - 1) / CHUNK;
    const int NPART = 512;
    size_t ND2 = (size_t)n * 64;         // half2 elements per feature buffer

    // workspace carve (~90 MB)
    char* p = (char*)d_ws;
    auto alloc = [&](size_t bytes) { char* r = p; p += align256(bytes); return r; };
    __half2*  yA       = (__half2*) alloc(ND2 * 4);
    __half2*  yB       = (__half2*) alloc(ND2 * 4);
    __half2*  U16      = (__half2*) alloc(ND2 * 4);
    int*      rowlist  = (int*)     alloc((size_t)(E + 16) * 4);  // +pad for int4 tail reads
    float*    dinv     = (float*)   alloc((size_t)n * 4);
    float*    dinv2    = (float*)   alloc((size_t)n * 4);
    float*    rec      = (float*)   alloc((size_t)n * 4);
    unsigned* cnt_row  = (unsigned*)alloc((size_t)n * 4);
    unsigned* cnt_col  = (unsigned*)alloc((size_t)n * 4);
    unsigned* colptr   = (unsigned*)alloc((size_t)(n + 1) * 4);
    unsigned* cursor   = (unsigned*)alloc((size_t)n * 4);
    float*    m_run    = (float*)   alloc((size_t)n * 4);
    float*    den_run  = (float*)   alloc((size_t)n * 4);
    unsigned* chunksum = (unsigned*)alloc((size_t)nchunks * 4);
    unsigned* chunkoff = (unsigned*)alloc((size_t)(nchunks + 1) * 4);
    float*    partial  = (float*)   alloc((size_t)NPART * DFEAT * 4);
    float*    wkq_ck   = (float*)   alloc((DFEAT + 1) * 4);
    if ((size_t)(p - (char*)d_ws) > ws_size) return;  // fail loud, not a crash

    hipMemsetAsync(cnt_row, 0, (size_t)n * 4, stream);
    hipMemsetAsync(cnt_col, 0, (size_t)n * 4, stream);

    count_kernel<<<(E + 255) / 256, 256, 0, stream>>>(eidx, cnt_row, cnt_col, E);
    dinv_kernel<<<(n + 255) / 256, 256, 0, stream>>>(cnt_row, dinv, dinv2, rec, n);
    chunk_reduce_kernel<<<nchunks, 256, 0, stream>>>(cnt_col, chunksum, n);
    scan_chunks_kernel<<<1, 64, 0, stream>>>(chunksum, chunkoff, colptr, nchunks, n, E);
    chunk_scan_kernel<<<nchunks, 256, 0, stream>>>(cnt_col, chunkoff, colptr, cursor, n);
    fill_csc_kernel<<<(E + 255) / 256, 256, 0, stream>>>(eidx, cursor, rowlist, E);

    scale_cvt_kernel<<<(n * 64 + 255) / 256, 256, 0, stream>>>(h_train, dinv, yA, n * 64);

    colmean_partial_kernel<<<NPART, 256, 0, stream>>>(h_ori, partial, n);
    wkq_kernel<<<1, 128, 0, stream>>>(partial, NPART, Wq, bq, Wk, bk, wkq_ck, 1.0f / (float)n);

    // hop 0: gathers yA; y1 -> yB; init online-softmax state
    prop0_kernel<<<(n + 3) / 4, 256, 0, stream>>>(yA, rowlist, colptr, dinv, rec, wkq_ck,
                                                  yB, U16, m_run, den_run, n);
    // hops 2..7: ping-pong yB <-> yA
    __half2* xin = yB; __half2* xout = yA;
    for (int t = 2; t <= 7; ++t) {
        prop_fused_kernel<<<(n + 3) / 4, 256, 0, stream>>>(xin, rowlist, colptr, dinv2, rec, wkq_ck,
                                                           xout, U16, m_run, den_run, n);
        __half2* tmp = xin; xin = xout; xout = tmp;
    }

    final_gemm_kernel<<<(n + 7) / 8, 256, 0, stream>>>(U16, den_run, Wv, bv, out, n);
}

// Round 5
// 917.259 us; speedup vs baseline: 1.6228x; 1.1470x over previous
//
#include <hip/hip_runtime.h>
#include <hip/hip_fp16.h>
#include <math.h>

#define DFEAT 128
#define QKD 32

static inline size_t align256(size_t x) { return (x + 255) & ~size_t(255); }

// ---- degree -------------------------------------------------------------

__global__ void count_row_kernel(const int* __restrict__ eidx, unsigned* __restrict__ cnt_row, int E) {
    int e = blockIdx.x * blockDim.x + threadIdx.x;
    if (e < E) atomicAdd(&cnt_row[eidx[e]], 1u);
}

// dinv = deg^-1/2 ; dinv2 = 1/deg ; rec = deg^1/2
__global__ void dinv_kernel(const unsigned* __restrict__ cnt_row, float* __restrict__ dinv,
                            float* __restrict__ dinv2, float* __restrict__ rec, int n) {
    int i = blockIdx.x * blockDim.x + threadIdx.x;
    if (i < n) {
        unsigned c = cnt_row[i];
        if (c < 1u) c = 1u;
        float fd = (float)c;
        float sq = sqrtf(fd);
        dinv[i] = 1.0f / sq;
        dinv2[i] = 1.0f / fd;
        rec[i] = sq;
    }
}

// ---- CSC build: block-aggregated 2-pass bucket partition ---------------
// bucket b covers cols [b*256, b*256+256); pk = (row<<8)|(col&255)

__global__ void bhist_kernel(const int* __restrict__ eidx, unsigned* __restrict__ bcount,
                             int E, int nbuk) {
    __shared__ unsigned h[512];
    for (int i = threadIdx.x; i < 512; i += 256) h[i] = 0;
    __syncthreads();
    int base = blockIdx.x * 8192;
    int end = base + 8192; if (end > E) end = E;
    for (int i = base + threadIdx.x; i < end; i += 256)
        atomicAdd(&h[(unsigned)eidx[E + i] >> 8], 1u);
    __syncthreads();
    for (int i = threadIdx.x; i < nbuk; i += 256)
        if (h[i]) atomicAdd(&bcount[i], h[i]);
}

__global__ void bscan_kernel(const unsigned* __restrict__ bcount, unsigned* __restrict__ bbase,
                             unsigned* __restrict__ bcur, unsigned* __restrict__ colptr,
                             int nbuk, int n, int E) {
    __shared__ unsigned s[512];
    int t = threadIdx.x;  // 512 threads
    unsigned v = (t < nbuk) ? bcount[t] : 0u;
    s[t] = v; __syncthreads();
    for (int off = 1; off < 512; off <<= 1) {
        unsigned u = (t >= off) ? s[t - off] : 0u;
        __syncthreads();
        s[t] += u;
        __syncthreads();
    }
    if (t < nbuk) { unsigned e = s[t] - v; bbase[t] = e; bcur[t] = e; }
    if (t == 0) { bbase[nbuk] = (unsigned)E; colptr[n] = (unsigned)E; }
}

__global__ void bscatter_kernel(const int* __restrict__ eidx, unsigned* __restrict__ bcur,
                                unsigned* __restrict__ pairs, int E) {
    __shared__ unsigned cnt[512];
    __shared__ unsigned cur[512];
    for (int i = threadIdx.x; i < 512; i += 256) cnt[i] = 0;
    __syncthreads();
    int base = blockIdx.x * 8192;
    int end = base + 8192; if (end > E) end = E;
    for (int i = base + threadIdx.x; i < end; i += 256)
        atomicAdd(&cnt[(unsigned)eidx[E + i] >> 8], 1u);
    __syncthreads();
    for (int i = threadIdx.x; i < 512; i += 256)
        cur[i] = cnt[i] ? atomicAdd(&bcur[i], cnt[i]) : 0u;
    __syncthreads();
    for (int i = base + threadIdx.x; i < end; i += 256) {
        int col = eidx[E + i];
        int row = eidx[i];
        unsigned pos = atomicAdd(&cur[(unsigned)col >> 8], 1u);
        pairs[pos] = ((unsigned)row << 8) | (unsigned)(col & 255);
    }
}

// one block per bucket: exact CSC placement in a 16KB window + colptr emit
__global__ void bsort_kernel(const unsigned* __restrict__ pairs, const unsigned* __restrict__ bbase,
                             unsigned* __restrict__ colptr, int* __restrict__ rowlist, int n) {
    __shared__ unsigned s[256];
    __shared__ unsigned cur[256];
    int b = blockIdx.x;
    unsigned beg = bbase[b], end = bbase[b + 1];
    int t = threadIdx.x;
    s[t] = 0;
    __syncthreads();
    for (unsigned i = beg + t; i < end; i += 256)
        atomicAdd(&s[pairs[i] & 255u], 1u);
    __syncthreads();
    unsigned v = s[t];
    for (int off = 1; off < 256; off <<= 1) {
        unsigned u = (t >= off) ? s[t - off] : 0u;
        __syncthreads();
        s[t] += u;
        __syncthreads();
    }
    unsigned start = beg + (s[t] - v);   // exclusive
    cur[t] = start;
    int c = b * 256 + t;
    if (c < n) colptr[c] = start;
    __syncthreads();
    for (unsigned i = beg + t; i < end; i += 256) {
        unsigned pk = pairs[i];
        unsigned pos = atomicAdd(&cur[pk & 255u], 1u);
        rowlist[pos] = (int)(pk >> 8);
    }
}

// ---- y0 = fp16(dinv * h_train) ----------------------------------------

__global__ void scale_cvt_kernel(const float* __restrict__ h, const float* __restrict__ dinv,
                                 __half2* __restrict__ y, int n64) {
    int i = blockIdx.x * blockDim.x + threadIdx.x;
    if (i < n64) {
        float d = dinv[i >> 6];
        float2 v = reinterpret_cast<const float2*>(h)[i];
        y[i] = __floats2half2_rn(d * v.x, d * v.y);
    }
}

// ---- query path ---------------------------------------------------------

__global__ void colmean_partial_kernel(const float* __restrict__ h, float* __restrict__ partial, int n) {
    __shared__ float s[256];
    int t = threadIdx.x;
    int col = t & 127;
    int half = t >> 7;
    float acc = 0.f;
    for (int r = blockIdx.x * 2 + half; r < n; r += gridDim.x * 2)
        acc += h[(size_t)r * DFEAT + col];
    s[t] = acc; __syncthreads();
    if (t < 128) partial[(size_t)blockIdx.x * DFEAT + t] = s[t] + s[t + 128];
}

__global__ void wkq_kernel(const float* __restrict__ partial, int nparts,
                           const float* __restrict__ Wq, const float* __restrict__ bq,
                           const float* __restrict__ Wk, const float* __restrict__ bk,
                           float* __restrict__ wkq_ck, float inv_n) {
    __shared__ float hb[DFEAT];
    __shared__ float qg[QKD];
    int t = threadIdx.x;  // 128 threads
    float acc = 0.f;
    for (int b = 0; b < nparts; ++b) acc += partial[(size_t)b * DFEAT + t];
    hb[t] = acc * inv_n;
    __syncthreads();
    if (t < QKD) {
        float a = bq[t];
        for (int d = 0; d < DFEAT; ++d) a += hb[d] * Wq[d * QKD + t];
        qg[t] = a;
    }
    __syncthreads();
    float w = 0.f;
    for (int q = 0; q < QKD; ++q) w += Wk[t * QKD + q] * qg[q];
    wkq_ck[t] = w;
    if (t == 0) {
        float c = 0.f;
        for (int q = 0; q < QKD; ++q) c += bk[q] * qg[q];
        wkq_ck[DFEAT] = c;
    }
}

// ---- propagate: 2 dest nodes per wave ----------------------------------
// half-wave (32 lanes) per node; uint2/lane = 4 fp16 feats; one full 256B row
// per half-wave per gather instruction (512B/wave-instruction).

__device__ __forceinline__ void acc4(const uint2* __restrict__ yq, int r, int sl, float4& a) {
    uint2 v = yq[(size_t)r * 32 + sl];
    float2 f0 = __half22float2(*reinterpret_cast<const __half2*>(&v.x));
    float2 f1 = __half22float2(*reinterpret_cast<const __half2*>(&v.y));
    a.x += f0.x; a.y += f0.y; a.z += f1.x; a.w += f1.y;
}

__device__ __forceinline__ float hred(float s) {   // reduce over 32-lane half
    s += __shfl_xor(s, 1, 64);  s += __shfl_xor(s, 2, 64);  s += __shfl_xor(s, 4, 64);
    s += __shfl_xor(s, 8, 64);  s += __shfl_xor(s, 16, 64);
    return s;
}

__device__ __forceinline__ float4 gatherw(const uint2* __restrict__ y,
                                          const int* __restrict__ rowlist,
                                          unsigned beg, unsigned deg, unsigned mxd, int sl) {
    float4 a = make_float4(0.f, 0.f, 0.f, 0.f);
    for (unsigned i = 0; i < mxd; i += 8) {
        unsigned rem = deg > i ? deg - i : 0;
        if (rem >= 8) {
            int4 q0 = *reinterpret_cast<const int4*>(&rowlist[beg + i]);
            int4 q1 = *reinterpret_cast<const int4*>(&rowlist[beg + i + 4]);
            acc4(y, q0.x, sl, a); acc4(y, q0.y, sl, a);
            acc4(y, q0.z, sl, a); acc4(y, q0.w, sl, a);
            acc4(y, q1.x, sl, a); acc4(y, q1.y, sl, a);
            acc4(y, q1.z, sl, a); acc4(y, q1.w, sl, a);
        } else if (rem) {
            for (unsigned k = 0; k < rem; ++k) acc4(y, rowlist[beg + i + k], sl, a);
        }
    }
    return a;
}

__device__ __forceinline__ uint2 pack4(float a, float b, float c, float d) {
    uint2 r;
    __half2 h0 = __floats2half2_rn(a, b), h1 = __floats2half2_rn(c, d);
    r.x = *reinterpret_cast<unsigned*>(&h0);
    r.y = *reinterpret_cast<unsigned*>(&h1);
    return r;
}

// hop0: a=x0+dinv*S (k=0), x1=x0-dinv*S (k=1); y1=dinv*x1; init {m,den,U}
__global__ void prop0_kernel(const uint2* __restrict__ y0,
                             const int* __restrict__ rowlist, const unsigned* __restrict__ colptr,
                             const float* __restrict__ dinv, const float* __restrict__ rec,
                             const float* __restrict__ wkq_ck,
                             uint2* __restrict__ yout, uint2* __restrict__ U,
                             float* __restrict__ m_run, float* __restrict__ den_run, int n) {
    int wid = threadIdx.x >> 6, lane = threadIdx.x & 63;
    int sub = lane >> 5, sl = lane & 31;
    int c = blockIdx.x * 8 + wid * 2 + sub;
    if (c >= n) c = n - 1;
    unsigned beg = colptr[c], end = colptr[c + 1];
    unsigned deg = end - beg;
    unsigned dego = __shfl_xor(deg, 32, 64);
    unsigned mxd = deg > dego ? deg : dego;
    float4 a = gatherw(y0, rowlist, beg, deg, mxd, sl);

    float dc = dinv[c], rc = rec[c];
    size_t off = (size_t)c * 32 + sl;
    uint2 bv = y0[off];
    float2 b0 = __half22float2(*reinterpret_cast<const __half2*>(&bv.x));
    float2 b1 = __half22float2(*reinterpret_cast<const __half2*>(&bv.y));
    float x0 = rc * b0.x, x1 = rc * b0.y, x2 = rc * b1.x, x3 = rc * b1.y;
    float p0 = dc * a.x, p1 = dc * a.y, p2 = dc * a.z, p3 = dc * a.w;
    float ad0 = x0 + p0, ad1 = x1 + p1, ad2 = x2 + p2, ad3 = x3 + p3;
    float sb0 = x0 - p0, sb1 = x1 - p1, sb2 = x2 - p2, sb3 = x3 - p3;
    yout[off] = pack4(dc * sb0, dc * sb1, dc * sb2, dc * sb3);

    const float scale = 0.08838834764831845f;  // 1/sqrt(128)
    float ck = wkq_ck[DFEAT];
    float4 wv = *reinterpret_cast<const float4*>(&wkq_ck[sl * 4]);
    float s0 = (hred(ad0 * wv.x + ad1 * wv.y + ad2 * wv.z + ad3 * wv.w) + ck) * scale;
    float s1 = (hred(sb0 * wv.x + sb1 * wv.y + sb2 * wv.z + sb3 * wv.w) + ck) * scale;
    float m = fmaxf(s0, s1);
    float e0 = expf(s0 - m), e1 = expf(s1 - m);
    U[off] = pack4(e0 * ad0 + e1 * sb0, e0 * ad1 + e1 * sb1,
                   e0 * ad2 + e1 * sb2, e0 * ad3 + e1 * sb3);
    if (sl == 0) { m_run[c] = m; den_run[c] = e0 + e1; }
}

// hops 2..7: y' = y - dinv2*S ; x' = rec*y' ; flash update {m,den,U}
__global__ void prop_fused_kernel(const uint2* __restrict__ y, const int* __restrict__ rowlist,
                                  const unsigned* __restrict__ colptr,
                                  const float* __restrict__ dinv2, const float* __restrict__ rec,
                                  const float* __restrict__ wkq_ck,
                                  uint2* __restrict__ yout, uint2* __restrict__ U,
                                  float* __restrict__ m_run, float* __restrict__ den_run, int n) {
    int wid = threadIdx.x >> 6, lane = threadIdx.x & 63;
    int sub = lane >> 5, sl = lane & 31;
    int c = blockIdx.x * 8 + wid * 2 + sub;
    if (c >= n) c = n - 1;
    unsigned beg = colptr[c], end = colptr[c + 1];
    unsigned deg = end - beg;
    unsigned dego = __shfl_xor(deg, 32, 64);
    unsigned mxd = deg > dego ? deg : dego;
    float4 a = gatherw(y, rowlist, beg, deg, mxd, sl);

    float d2 = dinv2[c], rc = rec[c];
    size_t off = (size_t)c * 32 + sl;
    uint2 bv = y[off];
    float2 b0 = __half22float2(*reinterpret_cast<const __half2*>(&bv.x));
    float2 b1 = __half22float2(*reinterpret_cast<const __half2*>(&bv.y));
    float y0 = b0.x - d2 * a.x, y1 = b0.y - d2 * a.y;
    float y2 = b1.x - d2 * a.z, y3 = b1.y - d2 * a.w;
    yout[off] = pack4(y0, y1, y2, y3);
    float x0 = rc * y0, x1 = rc * y1, x2 = rc * y2, x3 = rc * y3;

    const float scale = 0.08838834764831845f;
    float ck = wkq_ck[DFEAT];
    float4 wv = *reinterpret_cast<const float4*>(&wkq_ck[sl * 4]);
    float s = (hred(x0 * wv.x + x1 * wv.y + x2 * wv.z + x3 * wv.w) + ck) * scale;
    float m = m_run[c], den = den_run[c];
    float m2 = fmaxf(m, s);
    float alpha = expf(m - m2), beta = expf(s - m2);
    uint2 uv = U[off];
    float2 u0 = __half22float2(*reinterpret_cast<const __half2*>(&uv.x));
    float2 u1 = __half22float2(*reinterpret_cast<const __half2*>(&uv.y));
    U[off] = pack4(u0.x * alpha + beta * x0, u0.y * alpha + beta * x1,
                   u1.x * alpha + beta * x2, u1.y * alpha + beta * x3);
    if (sl == 0) { m_run[c] = m2; den_run[c] = den * alpha + beta; }
}

// ---- final: V = (U/den) @ Wv + bv -> d_out ----------------------------

__global__ void final_gemm_kernel(const __half2* __restrict__ U, const float* __restrict__ den_run,
                                  const float* __restrict__ Wv, const float* __restrict__ bv,
                                  float* __restrict__ out, int n) {
    __shared__ float M[8][DFEAT];
    int wid = threadIdx.x >> 6, lane = threadIdx.x & 63;
    int base = blockIdx.x * 8;
    for (int u = 0; u < 2; ++u) {
        int nn = base + wid * 2 + u;
        if (nn < n) {
            float inv = 1.0f / den_run[nn];
            float2 v = __half22float2(U[(size_t)nn * 64 + lane]);
            *reinterpret_cast<float2*>(&M[wid * 2 + u][lane * 2]) = make_float2(v.x * inv, v.y * inv);
        }
    }
    __syncthreads();
    int j = threadIdx.x & 127, hgrp = threadIdx.x >> 7;
    float bvj = bv[j];
    float acc0 = bvj, acc1 = bvj, acc2 = bvj, acc3 = bvj;
    for (int d = 0; d < DFEAT; ++d) {
        float w = Wv[d * DFEAT + j];
        acc0 += M[hgrp * 4 + 0][d] * w;
        acc1 += M[hgrp * 4 + 1][d] * w;
        acc2 += M[hgrp * 4 + 2][d] * w;
        acc3 += M[hgrp * 4 + 3][d] * w;
    }
    int n0 = base + hgrp * 4;
    if (n0 + 0 < n) out[(size_t)(n0 + 0) * DFEAT + j] = acc0;
    if (n0 + 1 < n) out[(size_t)(n0 + 1) * DFEAT + j] = acc1;
    if (n0 + 2 < n) out[(size_t)(n0 + 2) * DFEAT + j] = acc2;
    if (n0 + 3 < n) out[(size_t)(n0 + 3) * DFEAT + j] = acc3;
}

// ------------------------------------------------------------------------

extern "C" void kernel_launch(void* const* d_in, const int* in_sizes, int n_in,
                              void* d_out, int out_size, void* d_ws, size_t ws_size,
                              hipStream_t stream) {
    const float* h_train = (const float*)d_in[0];
    const float* h_ori   = (const float*)d_in[1];
    const int*   eidx    = (const int*)d_in[2];
    const float* Wq = (const float*)d_in[3];
    const float* bq = (const float*)d_in[4];
    const float* Wk = (const float*)d_in[5];
    const float* bk = (const float*)d_in[6];
    const float* Wv = (const float*)d_in[7];
    const float* bv = (const float*)d_in[8];
    float* out = (float*)d_out;

    const int n = in_sizes[0] / DFEAT;   // 100000
    const int E = in_sizes[2] / 2;       // 1600000
    const int NBUK = (n + 255) >> 8;     // 391
    const int EB = (E + 8191) / 8192;    // 196
    const int NPART = 512;
    size_t ND2 = (size_t)n * 64;         // half2 elems per feature buffer

    if (NBUK > 512) return;

    // workspace carve (~103 MB)
    char* p = (char*)d_ws;
    auto alloc = [&](size_t bytes) { char* r = p; p += align256(bytes); return r; };
    uint2*    yA       = (uint2*)   alloc(ND2 * 4);
    uint2*    yB       = (uint2*)   alloc(ND2 * 4);
    uint2*    U16      = (uint2*)   alloc(ND2 * 4);
    int*      rowlist  = (int*)     alloc((size_t)(E + 16) * 4);
    unsigned* pairs    = (unsigned*)alloc((size_t)E * 4);
    float*    dinv     = (float*)   alloc((size_t)n * 4);
    float*    dinv2    = (float*)   alloc((size_t)n * 4);
    float*    rec      = (float*)   alloc((size_t)n * 4);
    unsigned* cnt_row  = (unsigned*)alloc((size_t)n * 4);
    unsigned* colptr   = (unsigned*)alloc((size_t)(n + 1) * 4);
    unsigned* bcount   = (unsigned*)alloc((size_t)NBUK * 4);
    unsigned* bbase    = (unsigned*)alloc((size_t)(NBUK + 1) * 4);
    unsigned* bcur     = (unsigned*)alloc((size_t)NBUK * 4);
    float*    m_run    = (float*)   alloc((size_t)n * 4);
    float*    den_run  = (float*)   alloc((size_t)n * 4);
    float*    partial  = (float*)   alloc((size_t)NPART * DFEAT * 4);
    float*    wkq_ck   = (float*)   alloc((DFEAT + 1) * 4);
    if ((size_t)(p - (char*)d_ws) > ws_size) return;  // fail loud, not a crash

    hipMemsetAsync(cnt_row, 0, (size_t)n * 4, stream);
    hipMemsetAsync(bcount, 0, (size_t)NBUK * 4, stream);

    count_row_kernel<<<(E + 255) / 256, 256, 0, stream>>>(eidx, cnt_row, E);
    dinv_kernel<<<(n + 255) / 256, 256, 0, stream>>>(cnt_row, dinv, dinv2, rec, n);
    bhist_kernel<<<EB, 256, 0, stream>>>(eidx, bcount, E, NBUK);
    bscan_kernel<<<1, 512, 0, stream>>>(bcount, bbase, bcur, colptr, NBUK, n, E);
    bscatter_kernel<<<EB, 256, 0, stream>>>(eidx, bcur, pairs, E);
    bsort_kernel<<<NBUK, 256, 0, stream>>>(pairs, bbase, colptr, rowlist, n);

    scale_cvt_kernel<<<(n * 64 + 255) / 256, 256, 0, stream>>>(h_train, dinv, (__half2*)yA, n * 64);

    colmean_partial_kernel<<<NPART, 256, 0, stream>>>(h_ori, partial, n);
    wkq_kernel<<<1, 128, 0, stream>>>(partial, NPART, Wq, bq, Wk, bk, wkq_ck, 1.0f / (float)n);

    // hop 0: gathers yA; y1 -> yB; init online-softmax state
    prop0_kernel<<<(n + 7) / 8, 256, 0, stream>>>(yA, rowlist, colptr, dinv, rec, wkq_ck,
                                                  yB, U16, m_run, den_run, n);
    // hops 2..7: ping-pong yB <-> yA
    uint2* xin = yB; uint2* xout = yA;
    for (int t = 2; t <= 7; ++t) {
        prop_fused_kernel<<<(n + 7) / 8, 256, 0, stream>>>(xin, rowlist, colptr, dinv2, rec, wkq_ck,
                                                           xout, U16, m_run, den_run, n);
        uint2* tmp = xin; xin = xout; xout = tmp;
    }

    final_gemm_kernel<<<(n + 7) / 8, 256, 0, stream>>>((const __half2*)U16, den_run, Wv, bv, out, n);
}